// Round 9
// baseline (388.326 us; speedup 1.0000x reference)
//
#include <hip/hip_runtime.h>
#include <hip/hip_fp16.h>
#include <math.h>

// ---------------------------------------------------------------------------
// WaveRNN fused. Round 15: R8 persistent+prefetch structure with LDS OVERLAYS
// to restore concurrency. Model (validated R5/R6/R8):
//     time = (64 items/CU) x path / items_in_flight
// R8: path 10.9us (persistent+prefetch) but 8 blocks/CU (19.9KB LDS) -> 87us.
// R6: path 20us but 16 blocks/CU -> 80.6us. This round: short path AND high
// concurrency via lifetime-based LDS unions:
//   region A (8KB):  raw fp32 (dead after convert) U y1t (born in conv1)
//   region B (4.2KB): xbuf fp16 (dead after conv1) U y2t (born in conv2)
//   prefetch(i+1) issued AFTER conv2 (y1t's last read) -> lands in region A
//   during conv3+GRU+combine (~4us >> HBM latency).
// LDS 13456B -> 12 blocks/CU x 2 waves = 24 waves/CU. NITER=5 (grid ~12.8
// blocks/CU). Pads clobbered by overlays are rewritten per item (cheap).
// Duplicate tail prefetch removed (was +8MB FETCH in R8).
// Conv bodies byte-identical to R8 (verified): conv1 m=(delta<<2)|c zero-
// waste MFMA; conv2/conv3 transposed y1t/y2t, k = tap*Cin + ci.
// Poisons avoided: register prefetch across barriers (R13 spill), full-drain
// __syncthreads (R7), low-concurrency big-LDS blocks (R14).
// ---------------------------------------------------------------------------

typedef _Float16 h4 __attribute__((ext_vector_type(4)));
typedef _Float16 h8 __attribute__((ext_vector_type(8)));
typedef float f4 __attribute__((ext_vector_type(4)));

#define PACK_MAG0 0x57A9EDB1u
#define PACK_MAG1 0x1BDE9A75u
#define NITER 5

// LDS-visibility sync between the 2 waves WITHOUT draining vmcnt.
__device__ __forceinline__ void block_sync_lds()
{
    asm volatile("s_waitcnt lgkmcnt(0)" ::: "memory");
    __builtin_amdgcn_s_barrier();
}
__device__ __forceinline__ void wait_vm0()
{
    asm volatile("s_waitcnt vmcnt(0)" ::: "memory");
}

#if defined(__has_builtin)
#if __has_builtin(__builtin_amdgcn_global_load_lds)
#define HAVE_GLL 1
#endif
#endif

// Async 16B/lane global->LDS. LDS dest = uniform base + lane*16 (HW rule).
__device__ __forceinline__ void async_ld16(const float* g, float* lds)
{
#ifdef HAVE_GLL
    __builtin_amdgcn_global_load_lds(
        (const __attribute__((address_space(1))) void*)g,
        (__attribute__((address_space(3))) void*)lds, 16, 0, 0);
#else
    const int l = threadIdx.x & 63;
    ((float4*)lds)[l] = *(const float4*)g;   // g already lane-offset
#endif
}

// d_ws layout (halfs):
//   [0,1024)     wf1: [kk(2)][lane(64)][8]  A-frags conv1 (m=(delta<<2)|c,
//                                            tap = k - 4*delta - 1)
//   [1024,2048)  wf2: [kk(2)][lane(64)][8]  A-frags conv2 (k = tap*4 + ci)
//   [2048,3072)  wf3: [kk(2)][lane(64)][8]  A-frags conv3 (k = tap*8 + ci)
//   byte 8192    wihp: (96,20) fp32, col 19 = 0
//   byte 16384   flag[2]: pack-done magic
__global__ void pack_weights(const float* __restrict__ w1,
                             const float* __restrict__ w2,
                             const float* __restrict__ w3,
                             const float* __restrict__ w_ih,
                             _Float16* __restrict__ hws,
                             float* __restrict__ wihp,
                             unsigned int* __restrict__ flag)
{
    if (flag[0] == PACK_MAG0 && flag[1] == PACK_MAG1) return;  // uniform

    for (int i = threadIdx.x; i < 1024; i += 256) {
        int kk = i >> 9, l = (i >> 3) & 63, j = i & 7;
        int m = l & 15, oct = l >> 4;
        int k = kk * 32 + oct * 8 + j;
        int delta = m >> 2, c = m & 3;
        int tap = k - 4 * delta - 1;
        float v = (tap >= 0 && tap < 31) ? w1[c * 31 + tap] : 0.0f;
        hws[i] = (_Float16)v;
    }
    for (int i = threadIdx.x; i < 1024; i += 256) {
        int kk = i >> 9, l = (i >> 3) & 63, j = i & 7;
        int c = l & 15, k = kk * 32 + ((l >> 4) << 3) + j;
        int tap = k >> 2, ci = k & 3;
        float v = (c < 8 && tap < 15) ? w2[(c * 4 + ci) * 15 + tap] : 0.0f;
        hws[1024 + i] = (_Float16)v;
    }
    for (int i = threadIdx.x; i < 1024; i += 256) {
        int kk = i >> 9, l = (i >> 3) & 63, j = i & 7;
        int c = l & 15, k = kk * 32 + ((l >> 4) << 3) + j;
        int tap = k >> 3, ci = k & 7;
        float v = (tap < 7) ? w3[(c * 8 + ci) * 7 + tap] : 0.0f;
        hws[2048 + i] = (_Float16)v;
    }
    for (int idx = threadIdx.x; idx < 96 * 20; idx += 256) {
        int r = idx / 20, c = idx % 20;
        wihp[idx] = (c < 19) ? w_ih[r * 19 + c] : 0.0f;
    }
    __syncthreads();
    if (threadIdx.x == 0) { flag[0] = PACK_MAG0; flag[1] = PACK_MAG1; }
}

__global__ void __launch_bounds__(128, 6)
wavernn_fused(const float* __restrict__ past,      // (B,2000)
              const float* __restrict__ velocity,  // (B,)
              const float* __restrict__ log_pitch, // (B,)
              const float* __restrict__ time_in,   // (B,)
              const float* __restrict__ hidden,    // (B,32)
              const float* __restrict__ b1,
              const float* __restrict__ b2,
              const float* __restrict__ b3,
              const float* __restrict__ wihp,      // packed (96,20) fp32
              const float* __restrict__ w_hh,
              const float* __restrict__ b_ih, const float* __restrict__ b_hh,
              const float* __restrict__ w_proj, const float* __restrict__ b_proj,
              const _Float16* __restrict__ hws,    // packed weights (halfs)
              float* __restrict__ out, int B)
{
    // Region A (8KB): raw fp32[2048] (prefetch target, alive only in convert)
    //                 UNION y1t fp16[2048] (alive conv1..conv2).
    __shared__ __align__(16) float regA[2048];
    // Region B (4.2KB): xbuf fp16[2112] (alive convert..conv1)
    //                   UNION y2t fp16[1056] (alive conv2..conv3).
    __shared__ __align__(16) _Float16 regB[2112];
    __shared__ float G[192];        // gis[0..95] | ghs[96..191]
    __shared__ float rnnp[2][16];   // per-wave partial channel sums (conv3)
    __shared__ float hsl[32];       // current item hidden
    __shared__ float rnn3[4];       // vel, pitch, time

    float* const raw      = regA;
    _Float16* const y1t   = (_Float16*)regA;
    _Float16* const xbuf  = regB;
    _Float16* const y2t   = regB;

    const h8* const wf1 = (const h8*)hws;            // [kk][lane]
    const h8* const wf2 = (const h8*)(hws + 1024);
    const h8* const wf3 = (const h8*)(hws + 2048);

    const int tid = threadIdx.x;     // 0..127
    const int w   = tid >> 6;        // wave id 0/1
    const int l   = tid & 63;        // lane within wave
    const int o   = l >> 4;          // k-octet / D row-group
    const int q   = l & 15;          // tile column
    const f4 z4 = {0.0f, 0.0f, 0.0f, 0.0f};

    const int item0 = blockIdx.x * NITER;

    // ---------------- hoisted weight fragments (loop-invariant) ------------
    const h8 a10 = wf1[l],      a11 = wf1[64 + l];
    const h8 a20 = wf2[l],      a21 = wf2[64 + l];
    const h8 a30 = wf3[l],      a31 = wf3[64 + l];
    const float bv0 = b1[0], bv1 = b1[1], bv2 = b1[2], bv3 = b1[3];
    float b2v[4], b3v[4];
#pragma unroll
    for (int r = 0; r < 4; ++r) { b2v[r] = b2[(o * 4 + r) & 7];
                                  b3v[r] = b3[o * 4 + r]; }

    // ---------------- one-time pads (never clobbered by overlays) ----------
    // xbuf[2016..2111] (bytes 4032..4223): y2t spans only bytes 0..2111.
    if (tid < 96) xbuf[2016 + tid] = (_Float16)0.0f;

    // ---------------- async stage: 4 x 1KB per wave ------------------------
    auto stage_issue = [&](int ii) {
        const float* row = past + (size_t)ii * 2000;
#pragma unroll
        for (int c = 0; c < 4; ++c) {
            int foff = w * 1024 + c * 256 + l * 4;
            if (foff > 1996) foff = 1996;     // OOB guard; dup lands in pad
            async_ld16(row + foff, raw + w * 1024 + c * 256);
        }
    };

    // prologue: first item's fetch (the only exposed one per block)
    stage_issue(item0);

    for (int it = 0; it < NITER; ++it) {
        const int ii = item0 + it;
        if (ii >= B) break;

        // ---------- P0 convert: raw(fp32) -> xbuf(fp16) + tiny stages ------
        // Each wave converts exactly the half it prefetched (tid<64 <->
        // floats 0..1023 = wave0's half; tid 64..124 <-> wave1's half).
        wait_vm0();                       // raw(ii) landed
        if (tid < 32) hsl[tid] = hidden[(size_t)ii * 32 + tid];
        if (tid == 0) { rnn3[0] = velocity[ii];
                        rnn3[1] = log_pitch[ii];
                        rnn3[2] = time_in[ii]; }
        if (tid < 16) xbuf[tid] = (_Float16)0.0f;   // front pad (y2t clobbers)
        if (tid < 125) {
            const float4* r4 = (const float4*)raw + 4 * tid;
#pragma unroll
            for (int k = 0; k < 4; ++k) {
                float4 v = r4[k];
                h4 hv = {(_Float16)v.x, (_Float16)v.y,
                         (_Float16)v.z, (_Float16)v.w};
                *(h4*)(xbuf + 16 + 16 * tid + 4 * k) = hv;
            }
        }
        block_sync_lds();                 // xbuf ready; raw reads done

        // ---------- P1 conv1: xbuf -> y1t (region A reuse) -----------------
        if (tid < 28) y1t[tid] = (_Float16)0.0f;             // pos < 0 pad
        else if (tid < 48) y1t[2000 + tid] = (_Float16)0.0f; // 2028..2047 pad
#pragma unroll
        for (int Ti = 0; Ti < 4; ++Ti) {
            const int T = 4 * w + Ti;
            h8 x0 = *(const h8*)(xbuf + 256 * T + 16 * q + 8 * o);
            h8 x1 = *(const h8*)(xbuf + 256 * T + 16 * q + 32 + 8 * o);
            f4 d = __builtin_amdgcn_mfma_f32_16x16x32_f16(a10, x0, z4, 0, 0, 0);
            d = __builtin_amdgcn_mfma_f32_16x16x32_f16(a11, x1, d, 0, 0, 0);
            const int p = 64 * T + 4 * q + o;
            if (p < 500) {
                h4 wv = {(_Float16)fmaxf(d[0] + bv0, 0.0f),
                         (_Float16)fmaxf(d[1] + bv1, 0.0f),
                         (_Float16)fmaxf(d[2] + bv2, 0.0f),
                         (_Float16)fmaxf(d[3] + bv3, 0.0f)};
                *(h4*)(y1t + (7 + p) * 4) = wv;
            }
        }
        block_sync_lds();                 // y1t ready; xbuf reads done

        // ---------- P2 conv2: y1t -> y2t (region B reuse) ------------------
        if (tid < 24) y2t[tid] = (_Float16)0.0f;             // pos < 0 pad
        if (tid >= 96) y2t[928 + tid] = (_Float16)0.0f;      // 1024..1055 pad
#pragma unroll
        for (int Ti = 0; Ti < 4; ++Ti) {
            const int T = 4 * w + Ti;
            const int p = T * 16 + q;
            h8 x0 = *(const h8*)(y1t + 16 * p + 8 * o);        // kk0
            h8 x1 = *(const h8*)(y1t + 16 * p + 32 + 8 * o);   // kk1
            f4 d = __builtin_amdgcn_mfma_f32_16x16x32_f16(a20, x0, z4, 0, 0, 0);
            d = __builtin_amdgcn_mfma_f32_16x16x32_f16(a21, x1, d, 0, 0, 0);
            if (o < 2 && p < 125) {
                h4 wv = {(_Float16)fmaxf(d[0] + b2v[0], 0.0f),
                         (_Float16)fmaxf(d[1] + b2v[1], 0.0f),
                         (_Float16)fmaxf(d[2] + b2v[2], 0.0f),
                         (_Float16)fmaxf(d[3] + b2v[3], 0.0f)};
                *(h4*)(y2t + (3 + p) * 8 + o * 4) = wv;
            }
        }
        block_sync_lds();                 // y2t ready; y1t reads done

        // ---------- prefetch item ii+1 into region A (y1t now dead) --------
        // Flies under conv3 + GRU + combine (~4us >> HBM latency).
        if (it + 1 < NITER && ii + 1 < B) stage_issue(ii + 1);

        // ---------- P3 conv3: 1 tile per wave + partial mean ---------------
        {
            const int p = 16 * w + q;
            h8 x0 = *(const h8*)(y2t + 32 * p + 8 * o);
            h8 x1 = *(const h8*)(y2t + 32 * p + 32 + 8 * o);
            f4 d = __builtin_amdgcn_mfma_f32_16x16x32_f16(a30, x0, z4, 0, 0, 0);
            d = __builtin_amdgcn_mfma_f32_16x16x32_f16(a31, x1, d, 0, 0, 0);
#pragma unroll
            for (int r = 0; r < 4; ++r) {
                float v = fmaxf(d[r] + b3v[r], 0.0f);
                v += __shfl_xor(v, 1); v += __shfl_xor(v, 2);
                v += __shfl_xor(v, 4); v += __shfl_xor(v, 8);
                if (q == 0) rnnp[w][o * 4 + r] = v;   // partial (16 pos)
            }
        }
        block_sync_lds();

        // ---------- P4 GRU gates: 96 rows over threads 0..95 ---------------
        if (tid < 96) {
            float rv[20];
#pragma unroll
            for (int j = 0; j < 16; ++j)
                rv[j] = (rnnp[0][j] + rnnp[1][j]) * (1.0f / 32.0f);
            rv[16] = rnn3[0]; rv[17] = rnn3[1]; rv[18] = rnn3[2]; rv[19] = 0.0f;

            float a = b_ih[tid];
            const float4* wr = (const float4*)(wihp + tid * 20);
#pragma unroll
            for (int j = 0; j < 5; ++j) {
                float4 qv = wr[j];
                a += rv[4 * j] * qv.x + rv[4 * j + 1] * qv.y +
                     rv[4 * j + 2] * qv.z + rv[4 * j + 3] * qv.w;
            }
            G[tid] = a;

            float hv[32];
#pragma unroll
            for (int j = 0; j < 32; ++j) hv[j] = hsl[j];

            float g = b_hh[tid];
            const float4* wh = (const float4*)(w_hh + tid * 32);
#pragma unroll
            for (int j = 0; j < 8; ++j) {
                float4 qv = wh[j];
                g += hv[4 * j] * qv.x + hv[4 * j + 1] * qv.y +
                     hv[4 * j + 2] * qv.z + hv[4 * j + 3] * qv.w;
            }
            G[96 + tid] = g;
        }
        block_sync_lds();

        // ---------- P5 combine + projection (wave 0, lanes 0..31) ----------
        // No trailing barrier: wave1 may run ahead into P0(ii+1); it only
        // touches xbuf/raw halves it owns + its own vmcnt; hsl/rnn3 are
        // written by wave0 after its own P5 (program order).
        if (tid < 32) {
            const int j = tid;
            float r = 1.0f / (1.0f + expf(-(G[j] + G[96 + j])));
            float z = 1.0f / (1.0f + expf(-(G[32 + j] + G[128 + j])));
            float n = tanhf(G[64 + j] + r * G[160 + j]);
            float nh = (1.0f - z) * n + z * hsl[j];
            out[(size_t)2 * B + (size_t)ii * 32 + j] = nh;   // new_hidden

            float p0 = nh * w_proj[j];
            float p1 = nh * w_proj[32 + j];
            p0 += __shfl_xor(p0, 16); p1 += __shfl_xor(p1, 16);
            p0 += __shfl_xor(p0, 8);  p1 += __shfl_xor(p1, 8);
            p0 += __shfl_xor(p0, 4);  p1 += __shfl_xor(p1, 4);
            p0 += __shfl_xor(p0, 2);  p1 += __shfl_xor(p1, 2);
            p0 += __shfl_xor(p0, 1);  p1 += __shfl_xor(p1, 1);
            if (j == 0) {
                out[ii] = p0 + b_proj[0];                    // mu
                out[B + ii] = expf(p1 + b_proj[1]);          // sigma
            }
        }
    }
}

extern "C" void kernel_launch(void* const* d_in, const int* in_sizes, int n_in,
                              void* d_out, int out_size, void* d_ws, size_t ws_size,
                              hipStream_t stream)
{
    const float* past      = (const float*)d_in[0];
    const float* velocity  = (const float*)d_in[1];
    const float* log_pitch = (const float*)d_in[2];
    const float* time_in   = (const float*)d_in[3];
    const float* hidden    = (const float*)d_in[4];
    const float* w1  = (const float*)d_in[5];
    const float* b1  = (const float*)d_in[6];
    const float* w2  = (const float*)d_in[7];
    const float* b2  = (const float*)d_in[8];
    const float* w3  = (const float*)d_in[9];
    const float* b3  = (const float*)d_in[10];
    const float* wih = (const float*)d_in[11];
    const float* whh = (const float*)d_in[12];
    const float* bih = (const float*)d_in[13];
    const float* bhh = (const float*)d_in[14];
    const float* wpr = (const float*)d_in[15];
    const float* bpr = (const float*)d_in[16];

    const int B = in_sizes[0] / 2000;
    _Float16* hws = (_Float16*)d_ws;
    float* wihp = (float*)((char*)d_ws + 8192);            // (96,20) fp32
    unsigned int* flag = (unsigned int*)((char*)d_ws + 16384);

    pack_weights<<<dim3(1), dim3(256), 0, stream>>>(w1, w2, w3, wih,
                                                    hws, wihp, flag);

    const int nblk = (B + NITER - 1) / NITER;
    wavernn_fused<<<dim3(nblk), dim3(128), 0, stream>>>(
        past, velocity, log_pitch, time_in, hidden,
        b1, b2, b3, wihp, whh, bih, bhh, wpr, bpr,
        (const _Float16*)hws, (float*)d_out, B);
}

// Round 10
// 278.125 us; speedup vs baseline: 1.3962x; 1.3962x over previous
//
#include <hip/hip_runtime.h>
#include <hip/hip_fp16.h>
#include <math.h>

// ---------------------------------------------------------------------------
// WaveRNN fused. Round 16: R9 overlay structure, spill trigger reverted.
// R9's 100MB WRITE / 227MB FETCH = scratch spill (R13 signature), most
// likely caused by __launch_bounds__(128,6) squeezing VGPR cap 128->85.
// This round:
//   (1) __launch_bounds__(128,4) -- the R8-proven no-spill setting.
//   (2) G (GRU gates, 768B) overlaid into regB (y2t dead after conv3;
//       wave-1 runahead writes only regB bytes >= 2080, G spans 0..767,
//       so the no-trailing-barrier scheme stays race-free).
//       LDS 13456 -> 12688 (12800 rounded) -> 12 blocks/CU x 2 waves = 75%.
//   (3) NITER=5 (grid 3277 >= 12x256 keeps all LDS slots fed).
// Model (validated R5/R6/R8/R9): time = 64 items/CU x path / in-flight.
// Predicted: 64 x ~10.5us / 12 ~= 56-65us fused.
// Overlays (lifetime-disjoint, from R9):
//   region A (8KB):  raw fp32 (convert-only) U y1t (conv1..conv2)
//   region B (4.2KB): xbuf fp16 (convert..conv1) U y2t (conv2..conv3)
//                     U G (GRU..combine)
//   prefetch(i+1) issued AFTER conv2 (y1t's last read), lands during
//   conv3+GRU+combine (~4us >> HBM latency).
// Conv bodies byte-identical to R8/R9 (verified): conv1 m=(delta<<2)|c
// zero-waste MFMA; conv2/conv3 transposed y1t/y2t, k = tap*Cin + ci.
// Poisons: register prefetch across barriers (R13), launch_bounds(128,6)
// spill (R9/R15), full-drain __syncthreads (R7), big-LDS low-occ (R14).
// ---------------------------------------------------------------------------

typedef _Float16 h4 __attribute__((ext_vector_type(4)));
typedef _Float16 h8 __attribute__((ext_vector_type(8)));
typedef float f4 __attribute__((ext_vector_type(4)));

#define PACK_MAG0 0x57A9EDB1u
#define PACK_MAG1 0x1BDE9A75u
#define NITER 5

// LDS-visibility sync between the 2 waves WITHOUT draining vmcnt.
__device__ __forceinline__ void block_sync_lds()
{
    asm volatile("s_waitcnt lgkmcnt(0)" ::: "memory");
    __builtin_amdgcn_s_barrier();
}
__device__ __forceinline__ void wait_vm0()
{
    asm volatile("s_waitcnt vmcnt(0)" ::: "memory");
}

#if defined(__has_builtin)
#if __has_builtin(__builtin_amdgcn_global_load_lds)
#define HAVE_GLL 1
#endif
#endif

// Async 16B/lane global->LDS. LDS dest = uniform base + lane*16 (HW rule).
__device__ __forceinline__ void async_ld16(const float* g, float* lds)
{
#ifdef HAVE_GLL
    __builtin_amdgcn_global_load_lds(
        (const __attribute__((address_space(1))) void*)g,
        (__attribute__((address_space(3))) void*)lds, 16, 0, 0);
#else
    const int l = threadIdx.x & 63;
    ((float4*)lds)[l] = *(const float4*)g;   // g already lane-offset
#endif
}

// d_ws layout (halfs):
//   [0,1024)     wf1: [kk(2)][lane(64)][8]  A-frags conv1 (m=(delta<<2)|c,
//                                            tap = k - 4*delta - 1)
//   [1024,2048)  wf2: [kk(2)][lane(64)][8]  A-frags conv2 (k = tap*4 + ci)
//   [2048,3072)  wf3: [kk(2)][lane(64)][8]  A-frags conv3 (k = tap*8 + ci)
//   byte 8192    wihp: (96,20) fp32, col 19 = 0
//   byte 16384   flag[2]: pack-done magic
__global__ void pack_weights(const float* __restrict__ w1,
                             const float* __restrict__ w2,
                             const float* __restrict__ w3,
                             const float* __restrict__ w_ih,
                             _Float16* __restrict__ hws,
                             float* __restrict__ wihp,
                             unsigned int* __restrict__ flag)
{
    if (flag[0] == PACK_MAG0 && flag[1] == PACK_MAG1) return;  // uniform

    for (int i = threadIdx.x; i < 1024; i += 256) {
        int kk = i >> 9, l = (i >> 3) & 63, j = i & 7;
        int m = l & 15, oct = l >> 4;
        int k = kk * 32 + oct * 8 + j;
        int delta = m >> 2, c = m & 3;
        int tap = k - 4 * delta - 1;
        float v = (tap >= 0 && tap < 31) ? w1[c * 31 + tap] : 0.0f;
        hws[i] = (_Float16)v;
    }
    for (int i = threadIdx.x; i < 1024; i += 256) {
        int kk = i >> 9, l = (i >> 3) & 63, j = i & 7;
        int c = l & 15, k = kk * 32 + ((l >> 4) << 3) + j;
        int tap = k >> 2, ci = k & 3;
        float v = (c < 8 && tap < 15) ? w2[(c * 4 + ci) * 15 + tap] : 0.0f;
        hws[1024 + i] = (_Float16)v;
    }
    for (int i = threadIdx.x; i < 1024; i += 256) {
        int kk = i >> 9, l = (i >> 3) & 63, j = i & 7;
        int c = l & 15, k = kk * 32 + ((l >> 4) << 3) + j;
        int tap = k >> 3, ci = k & 7;
        float v = (tap < 7) ? w3[(c * 8 + ci) * 7 + tap] : 0.0f;
        hws[2048 + i] = (_Float16)v;
    }
    for (int idx = threadIdx.x; idx < 96 * 20; idx += 256) {
        int r = idx / 20, c = idx % 20;
        wihp[idx] = (c < 19) ? w_ih[r * 19 + c] : 0.0f;
    }
    __syncthreads();
    if (threadIdx.x == 0) { flag[0] = PACK_MAG0; flag[1] = PACK_MAG1; }
}

__global__ void __launch_bounds__(128, 4)
wavernn_fused(const float* __restrict__ past,      // (B,2000)
              const float* __restrict__ velocity,  // (B,)
              const float* __restrict__ log_pitch, // (B,)
              const float* __restrict__ time_in,   // (B,)
              const float* __restrict__ hidden,    // (B,32)
              const float* __restrict__ b1,
              const float* __restrict__ b2,
              const float* __restrict__ b3,
              const float* __restrict__ wihp,      // packed (96,20) fp32
              const float* __restrict__ w_hh,
              const float* __restrict__ b_ih, const float* __restrict__ b_hh,
              const float* __restrict__ w_proj, const float* __restrict__ b_proj,
              const _Float16* __restrict__ hws,    // packed weights (halfs)
              float* __restrict__ out, int B)
{
    // Region A (8KB): raw fp32[2048] (convert-only) U y1t fp16 (conv1..conv2)
    __shared__ __align__(16) float regA[2048];
    // Region B (4.2KB): xbuf fp16[2112] (convert..conv1)
    //                   U y2t fp16[1056] (conv2..conv3)
    //                   U G fp32[192] (GRU..combine, bytes 0..767)
    __shared__ __align__(16) _Float16 regB[2112];
    __shared__ float rnnp[2][16];   // per-wave partial channel sums (conv3)
    __shared__ float hsl[32];       // current item hidden
    __shared__ float rnn3[4];       // vel, pitch, time

    float* const raw      = regA;
    _Float16* const y1t   = (_Float16*)regA;
    _Float16* const xbuf  = regB;
    _Float16* const y2t   = regB;
    float* const G        = (float*)regB;    // overlays y2t (dead after P3)

    const h8* const wf1 = (const h8*)hws;            // [kk][lane]
    const h8* const wf2 = (const h8*)(hws + 1024);
    const h8* const wf3 = (const h8*)(hws + 2048);

    const int tid = threadIdx.x;     // 0..127
    const int w   = tid >> 6;        // wave id 0/1
    const int l   = tid & 63;        // lane within wave
    const int o   = l >> 4;          // k-octet / D row-group
    const int q   = l & 15;          // tile column
    const f4 z4 = {0.0f, 0.0f, 0.0f, 0.0f};

    const int item0 = blockIdx.x * NITER;

    // ---------------- hoisted weight fragments (loop-invariant) ------------
    const h8 a10 = wf1[l],      a11 = wf1[64 + l];
    const h8 a20 = wf2[l],      a21 = wf2[64 + l];
    const h8 a30 = wf3[l],      a31 = wf3[64 + l];
    const float bv0 = b1[0], bv1 = b1[1], bv2 = b1[2], bv3 = b1[3];
    float b2v[4], b3v[4];
#pragma unroll
    for (int r = 0; r < 4; ++r) { b2v[r] = b2[(o * 4 + r) & 7];
                                  b3v[r] = b3[o * 4 + r]; }

    // ---------------- one-time pads (never clobbered by overlays) ----------
    // xbuf[2016..2111] (bytes 4032..4223): y2t spans bytes 0..2111, G 0..767.
    if (tid < 96) xbuf[2016 + tid] = (_Float16)0.0f;

    // ---------------- async stage: 4 x 1KB per wave ------------------------
    auto stage_issue = [&](int ii) {
        const float* row = past + (size_t)ii * 2000;
#pragma unroll
        for (int c = 0; c < 4; ++c) {
            int foff = w * 1024 + c * 256 + l * 4;
            if (foff > 1996) foff = 1996;     // OOB guard; dup lands in pad
            async_ld16(row + foff, raw + w * 1024 + c * 256);
        }
    };

    // prologue: first item's fetch (the only exposed one per block)
    stage_issue(item0);

    for (int it = 0; it < NITER; ++it) {
        const int ii = item0 + it;
        if (ii >= B) break;

        // ---------- P0 convert: raw(fp32) -> xbuf(fp16) + tiny stages ------
        // Each wave converts exactly the half it prefetched.
        wait_vm0();                       // raw(ii) landed
        if (tid < 32) hsl[tid] = hidden[(size_t)ii * 32 + tid];
        if (tid == 0) { rnn3[0] = velocity[ii];
                        rnn3[1] = log_pitch[ii];
                        rnn3[2] = time_in[ii]; }
        if (tid < 16) xbuf[tid] = (_Float16)0.0f;   // front pad (G clobbers)
        if (tid < 125) {
            const float4* r4 = (const float4*)raw + 4 * tid;
#pragma unroll
            for (int k = 0; k < 4; ++k) {
                float4 v = r4[k];
                h4 hv = {(_Float16)v.x, (_Float16)v.y,
                         (_Float16)v.z, (_Float16)v.w};
                *(h4*)(xbuf + 16 + 16 * tid + 4 * k) = hv;
            }
        }
        block_sync_lds();                 // xbuf ready; raw reads done

        // ---------- P1 conv1: xbuf -> y1t (region A reuse) -----------------
        if (tid < 28) y1t[tid] = (_Float16)0.0f;             // pos < 0 pad
        else if (tid < 48) y1t[2000 + tid] = (_Float16)0.0f; // 2028..2047 pad
#pragma unroll
        for (int Ti = 0; Ti < 4; ++Ti) {
            const int T = 4 * w + Ti;
            h8 x0 = *(const h8*)(xbuf + 256 * T + 16 * q + 8 * o);
            h8 x1 = *(const h8*)(xbuf + 256 * T + 16 * q + 32 + 8 * o);
            f4 d = __builtin_amdgcn_mfma_f32_16x16x32_f16(a10, x0, z4, 0, 0, 0);
            d = __builtin_amdgcn_mfma_f32_16x16x32_f16(a11, x1, d, 0, 0, 0);
            const int p = 64 * T + 4 * q + o;
            if (p < 500) {
                h4 wv = {(_Float16)fmaxf(d[0] + bv0, 0.0f),
                         (_Float16)fmaxf(d[1] + bv1, 0.0f),
                         (_Float16)fmaxf(d[2] + bv2, 0.0f),
                         (_Float16)fmaxf(d[3] + bv3, 0.0f)};
                *(h4*)(y1t + (7 + p) * 4) = wv;
            }
        }
        block_sync_lds();                 // y1t ready; xbuf reads done

        // ---------- P2 conv2: y1t -> y2t (region B reuse) ------------------
        if (tid < 24) y2t[tid] = (_Float16)0.0f;             // pos < 0 pad
        if (tid >= 96) y2t[928 + tid] = (_Float16)0.0f;      // 1024..1055 pad
#pragma unroll
        for (int Ti = 0; Ti < 4; ++Ti) {
            const int T = 4 * w + Ti;
            const int p = T * 16 + q;
            h8 x0 = *(const h8*)(y1t + 16 * p + 8 * o);        // kk0
            h8 x1 = *(const h8*)(y1t + 16 * p + 32 + 8 * o);   // kk1
            f4 d = __builtin_amdgcn_mfma_f32_16x16x32_f16(a20, x0, z4, 0, 0, 0);
            d = __builtin_amdgcn_mfma_f32_16x16x32_f16(a21, x1, d, 0, 0, 0);
            if (o < 2 && p < 125) {
                h4 wv = {(_Float16)fmaxf(d[0] + b2v[0], 0.0f),
                         (_Float16)fmaxf(d[1] + b2v[1], 0.0f),
                         (_Float16)fmaxf(d[2] + b2v[2], 0.0f),
                         (_Float16)fmaxf(d[3] + b2v[3], 0.0f)};
                *(h4*)(y2t + (3 + p) * 8 + o * 4) = wv;
            }
        }
        block_sync_lds();                 // y2t ready; y1t reads done

        // ---------- prefetch item ii+1 into region A (y1t now dead) --------
        // Flies under conv3 + GRU + combine (~4us >> HBM latency).
        if (it + 1 < NITER && ii + 1 < B) stage_issue(ii + 1);

        // ---------- P3 conv3: 1 tile per wave + partial mean ---------------
        {
            const int p = 16 * w + q;
            h8 x0 = *(const h8*)(y2t + 32 * p + 8 * o);
            h8 x1 = *(const h8*)(y2t + 32 * p + 32 + 8 * o);
            f4 d = __builtin_amdgcn_mfma_f32_16x16x32_f16(a30, x0, z4, 0, 0, 0);
            d = __builtin_amdgcn_mfma_f32_16x16x32_f16(a31, x1, d, 0, 0, 0);
#pragma unroll
            for (int r = 0; r < 4; ++r) {
                float v = fmaxf(d[r] + b3v[r], 0.0f);
                v += __shfl_xor(v, 1); v += __shfl_xor(v, 2);
                v += __shfl_xor(v, 4); v += __shfl_xor(v, 8);
                if (q == 0) rnnp[w][o * 4 + r] = v;   // partial (16 pos)
            }
        }
        block_sync_lds();                 // y2t reads done -> G may overwrite

        // ---------- P4 GRU gates: 96 rows over threads 0..95 ---------------
        if (tid < 96) {
            float rv[20];
#pragma unroll
            for (int j = 0; j < 16; ++j)
                rv[j] = (rnnp[0][j] + rnnp[1][j]) * (1.0f / 32.0f);
            rv[16] = rnn3[0]; rv[17] = rnn3[1]; rv[18] = rnn3[2]; rv[19] = 0.0f;

            float a = b_ih[tid];
            const float4* wr = (const float4*)(wihp + tid * 20);
#pragma unroll
            for (int j = 0; j < 5; ++j) {
                float4 qv = wr[j];
                a += rv[4 * j] * qv.x + rv[4 * j + 1] * qv.y +
                     rv[4 * j + 2] * qv.z + rv[4 * j + 3] * qv.w;
            }
            G[tid] = a;

            float hv[32];
#pragma unroll
            for (int j = 0; j < 32; ++j) hv[j] = hsl[j];

            float g = b_hh[tid];
            const float4* wh = (const float4*)(w_hh + tid * 32);
#pragma unroll
            for (int j = 0; j < 8; ++j) {
                float4 qv = wh[j];
                g += hv[4 * j] * qv.x + hv[4 * j + 1] * qv.y +
                     hv[4 * j + 2] * qv.z + hv[4 * j + 3] * qv.w;
            }
            G[96 + tid] = g;
        }
        block_sync_lds();

        // ---------- P5 combine + projection (wave 0, lanes 0..31) ----------
        // No trailing barrier: wave1 runs ahead into P0(ii+1); its writes
        // touch only regB bytes >= 2080 (convert half) -- G (bytes 0..767)
        // is read-safe; hsl/rnn3 are written by wave0 after its own P5.
        if (tid < 32) {
            const int j = tid;
            float r = 1.0f / (1.0f + expf(-(G[j] + G[96 + j])));
            float z = 1.0f / (1.0f + expf(-(G[32 + j] + G[128 + j])));
            float n = tanhf(G[64 + j] + r * G[160 + j]);
            float nh = (1.0f - z) * n + z * hsl[j];
            out[(size_t)2 * B + (size_t)ii * 32 + j] = nh;   // new_hidden

            float p0 = nh * w_proj[j];
            float p1 = nh * w_proj[32 + j];
            p0 += __shfl_xor(p0, 16); p1 += __shfl_xor(p1, 16);
            p0 += __shfl_xor(p0, 8);  p1 += __shfl_xor(p1, 8);
            p0 += __shfl_xor(p0, 4);  p1 += __shfl_xor(p1, 4);
            p0 += __shfl_xor(p0, 2);  p1 += __shfl_xor(p1, 2);
            p0 += __shfl_xor(p0, 1);  p1 += __shfl_xor(p1, 1);
            if (j == 0) {
                out[ii] = p0 + b_proj[0];                    // mu
                out[B + ii] = expf(p1 + b_proj[1]);          // sigma
            }
        }
    }
}

extern "C" void kernel_launch(void* const* d_in, const int* in_sizes, int n_in,
                              void* d_out, int out_size, void* d_ws, size_t ws_size,
                              hipStream_t stream)
{
    const float* past      = (const float*)d_in[0];
    const float* velocity  = (const float*)d_in[1];
    const float* log_pitch = (const float*)d_in[2];
    const float* time_in   = (const float*)d_in[3];
    const float* hidden    = (const float*)d_in[4];
    const float* w1  = (const float*)d_in[5];
    const float* b1  = (const float*)d_in[6];
    const float* w2  = (const float*)d_in[7];
    const float* b2  = (const float*)d_in[8];
    const float* w3  = (const float*)d_in[9];
    const float* b3  = (const float*)d_in[10];
    const float* wih = (const float*)d_in[11];
    const float* whh = (const float*)d_in[12];
    const float* bih = (const float*)d_in[13];
    const float* bhh = (const float*)d_in[14];
    const float* wpr = (const float*)d_in[15];
    const float* bpr = (const float*)d_in[16];

    const int B = in_sizes[0] / 2000;
    _Float16* hws = (_Float16*)d_ws;
    float* wihp = (float*)((char*)d_ws + 8192);            // (96,20) fp32
    unsigned int* flag = (unsigned int*)((char*)d_ws + 16384);

    pack_weights<<<dim3(1), dim3(256), 0, stream>>>(w1, w2, w3, wih,
                                                    hws, wihp, flag);

    const int nblk = (B + NITER - 1) / NITER;
    wavernn_fused<<<dim3(nblk), dim3(128), 0, stream>>>(
        past, velocity, log_pitch, time_in, hidden,
        b1, b2, b3, wihp, whh, bih, bhh, wpr, bpr,
        (const _Float16*)hws, (float*)d_out, B);
}